// Round 1
// baseline (211.283 us; speedup 1.0000x reference)
//
#include <hip/hip_runtime.h>
#include <math.h>

#define BB 256
#define VV 400000
#define NR 500
#define D1 128
#define D2 128
#define PP 64
#define KK 30
#define TT 20
#define BN_EPS 1e-5f
// 1/sqrt(K*T) = 1/sqrt(600)
#define FACTOR 0.04082482904638631f

// ---------------- Kernel 1: compute x[B][K] into workspace ----------------
// One block (1 wave, 64 threads) per batch row.
__global__ __launch_bounds__(64) void lowfer_stage1(
    const int* __restrict__ e1_idx, const int* __restrict__ r_idx,
    const float* __restrict__ E, const float* __restrict__ R,
    const float* __restrict__ proj, const int* __restrict__ idx,
    const float* __restrict__ g0, const float* __restrict__ b0,
    const float* __restrict__ m0, const float* __restrict__ v0,
    const float* __restrict__ g1, const float* __restrict__ b1,
    const float* __restrict__ m1, const float* __restrict__ v1,
    float* __restrict__ xw)
{
    __shared__ float e1s[D1];
    __shared__ float rs[D1];
    __shared__ float ses[PP];
    __shared__ float srs[PP];
    __shared__ float xsq[KK];

    const int tid = threadIdx.x;
    const int row = blockIdx.x;

    const int eix = e1_idx[row];
    const int rix = r_idx[row];

    // Load e1 row (with BN0) and r row into LDS. 64 threads x 2 elems.
    for (int j = tid; j < D1; j += 64) {
        float ev = E[(size_t)eix * D1 + j];
        e1s[j] = (ev - m0[j]) * rsqrtf(v0[j] + BN_EPS) * g0[j] + b0[j];
        rs[j]  = R[(size_t)rix * D2 + j];
    }
    __syncthreads();

    // se[p], sr[p] for p = tid (P == 64 == wave size). proj load is coalesced.
    float se = 0.f, sr = 0.f;
#pragma unroll 4
    for (int d = 0; d < D1; ++d) {
        float pv = proj[d * PP + tid];
        se += e1s[d] * pv;
        sr += rs[d]  * pv;
    }
    ses[tid] = se;
    srs[tid] = sr;
    __syncthreads();

    // y[k] for k = tid < K, then signed sqrt.
    float xv = 0.f;
    if (tid < KK) {
        float y = 0.f;
        for (int t = 0; t < TT; ++t) {
            int i0 = idx[(tid * TT + t) * 2 + 0];
            int i1 = idx[(tid * TT + t) * 2 + 1];
            y += ses[i0] * srs[i1];
        }
        y *= FACTOR;
        float s = (y > 0.f) ? 1.f : ((y < 0.f) ? -1.f : 0.f);
        xv = s * sqrtf(fabsf(y) + 1e-12f);
        xsq[tid] = xv * xv;
    }
    __syncthreads();

    if (tid < KK) {
        float ss = 0.f;
#pragma unroll
        for (int k = 0; k < KK; ++k) ss += xsq[k];   // broadcast LDS reads
        float nrm = fmaxf(sqrtf(ss), 1e-12f);
        float xn = xv / nrm;
        xn = (xn - m1[tid]) * rsqrtf(v1[tid] + BN_EPS) * g1[tid] + b1[tid];
        xw[row * KK + tid] = xn;
    }
}

// ---------------- Kernel 2: out[b][v] = sigmoid(x[b] . E[v][0:K]) ----------
// One thread per v column; loop over all B rows in LDS-staged tiles of 64.
#define BTILE 64
__global__ __launch_bounds__(256) void lowfer_stage2(
    const float* __restrict__ E, const float* __restrict__ xw,
    float* __restrict__ out)
{
    __shared__ float xt[BTILE * KK];   // 7.5 KB

    const int tid = threadIdx.x;
    const int v = blockIdx.x * 256 + tid;
    const bool valid = (v < VV);

    // Load E[v][0:30] into registers: 7 x float4 + 1 x float2 (row is 512B-aligned).
    float e[KK];
    if (valid) {
        const float4* Ep = (const float4*)(E + (size_t)v * D1);
#pragma unroll
        for (int q = 0; q < 7; ++q) {
            float4 t4 = Ep[q];
            e[q * 4 + 0] = t4.x; e[q * 4 + 1] = t4.y;
            e[q * 4 + 2] = t4.z; e[q * 4 + 3] = t4.w;
        }
        float2 t2 = *(const float2*)(E + (size_t)v * D1 + 28);
        e[28] = t2.x; e[29] = t2.y;
    }

    for (int bt = 0; bt < BB / BTILE; ++bt) {
        __syncthreads();   // protect xt from previous tile's readers
        for (int j = tid; j < BTILE * KK; j += 256)
            xt[j] = xw[bt * BTILE * KK + j];
        __syncthreads();

        if (valid) {
#pragma unroll 2
            for (int b = 0; b < BTILE; ++b) {
                const float* xr = &xt[b * KK];
                // 4 partial accumulators to break the FMA dependence chain.
                float a0 = 0.f, a1 = 0.f, a2 = 0.f, a3 = 0.f;
#pragma unroll
                for (int k = 0; k < 28; k += 4) {
                    a0 += xr[k + 0] * e[k + 0];
                    a1 += xr[k + 1] * e[k + 1];
                    a2 += xr[k + 2] * e[k + 2];
                    a3 += xr[k + 3] * e[k + 3];
                }
                a0 += xr[28] * e[28];
                a1 += xr[29] * e[29];
                float acc = (a0 + a1) + (a2 + a3);
                float sg = 1.f / (1.f + __expf(-acc));
                __builtin_nontemporal_store(sg, &out[(size_t)(bt * BTILE + b) * VV + v]);
            }
        }
    }
}

extern "C" void kernel_launch(void* const* d_in, const int* in_sizes, int n_in,
                              void* d_out, int out_size, void* d_ws, size_t ws_size,
                              hipStream_t stream) {
    const int*   e1_idx = (const int*)  d_in[0];
    const int*   r_idx  = (const int*)  d_in[1];
    const float* E      = (const float*)d_in[2];
    const float* R      = (const float*)d_in[3];
    const float* proj   = (const float*)d_in[4];
    const int*   idx    = (const int*)  d_in[5];
    const float* g0     = (const float*)d_in[6];
    const float* b0     = (const float*)d_in[7];
    const float* m0     = (const float*)d_in[8];
    const float* v0     = (const float*)d_in[9];
    const float* g1     = (const float*)d_in[10];
    const float* b1     = (const float*)d_in[11];
    const float* m1     = (const float*)d_in[12];
    const float* v1     = (const float*)d_in[13];
    float* out = (float*)d_out;
    float* xw  = (float*)d_ws;   // B*K floats = 30 KB

    lowfer_stage1<<<BB, 64, 0, stream>>>(e1_idx, r_idx, E, R, proj, idx,
                                         g0, b0, m0, v0, g1, b1, m1, v1, xw);

    int grid2 = (VV + 255) / 256;
    lowfer_stage2<<<grid2, 256, 0, stream>>>(E, xw, out);
}